// Round 1
// baseline (141.729 us; speedup 1.0000x reference)
//
#include <hip/hip_runtime.h>
#include <hip/hip_bf16.h>

// Problem constants (match reference)
#define N_TERMS 2097152
#define B_SEGS  8192
#define D_DIM   64
#define TERMS_PER_GROUP 16   // one 16-lane group handles 16 consecutive terms
#define GROUP_LANES     16

__global__ __launch_bounds__(256) void iafm_kernel(
    const int*   __restrict__ feat_idxs,   // [N,2]
    const int*   __restrict__ intr_idxs,   // [N]
    const float* __restrict__ intr_divs,   // [N]
    const int*   __restrict__ segment_ids, // [N] sorted
    const float* __restrict__ vecs,        // [N_FEATS, 64]
    const float* __restrict__ intr_W,      // [N_INTRS, 1]
    const float* __restrict__ intr_b,      // [1]
    float*       __restrict__ out)         // [B]
{
    const int tid   = blockIdx.x * blockDim.x + threadIdx.x;
    const int group = tid >> 4;        // 16 lanes per group
    const int lane  = tid & 15;

    const int base = group * TERMS_PER_GROUP;
    if (base >= N_TERMS) return;

    const float bias = intr_b[0];

    // Per-lane metadata for term (base + lane); coalesced loads.
    const int  myterm = base + lane;
    const int2 fp  = ((const int2*)feat_idxs)[myterm];
    const int  ii  = intr_idxs[myterm];
    const float dv = intr_divs[myterm];
    const int  sg  = segment_ids[myterm];
    const float wod = intr_W[ii] / dv;   // w / div for my term

    float acc = 0.0f;
    int   cur_seg = -1;

    #pragma unroll
    for (int c = 0; c < TERMS_PER_GROUP; ++c) {
        const int f0  = __shfl(fp.x, c, GROUP_LANES);
        const int f1  = __shfl(fp.y, c, GROUP_LANES);
        const int seg = __shfl(sg,   c, GROUP_LANES);
        const float w = __shfl(wod,  c, GROUP_LANES);

        // 16 lanes x float4 = one 256B row each, fully coalesced.
        const float4 a = *(const float4*)(vecs + f0 * D_DIM + lane * 4);
        const float4 v = *(const float4*)(vecs + f1 * D_DIM + lane * 4);
        float d = a.x * v.x + a.y * v.y + a.z * v.z + a.w * v.w;

        // butterfly reduce across the 16-lane group
        d += __shfl_xor(d, 1, GROUP_LANES);
        d += __shfl_xor(d, 2, GROUP_LANES);
        d += __shfl_xor(d, 4, GROUP_LANES);
        d += __shfl_xor(d, 8, GROUP_LANES);

        const float term = w * d + bias;

        if (seg != cur_seg) {
            if (cur_seg >= 0 && lane == 0) atomicAdd(&out[cur_seg], acc);
            cur_seg = seg;
            acc = term;
        } else {
            acc += term;
        }
    }
    if (lane == 0 && cur_seg >= 0) atomicAdd(&out[cur_seg], acc);
}

extern "C" void kernel_launch(void* const* d_in, const int* in_sizes, int n_in,
                              void* d_out, int out_size, void* d_ws, size_t ws_size,
                              hipStream_t stream) {
    const int*   feat_idxs   = (const int*)  d_in[0];
    const int*   intr_idxs   = (const int*)  d_in[1];
    const float* intr_divs   = (const float*)d_in[2];
    const int*   segment_ids = (const int*)  d_in[3];
    const float* vecs        = (const float*)d_in[4];
    const float* intr_W      = (const float*)d_in[5];
    const float* intr_b      = (const float*)d_in[6];
    float*       out         = (float*)d_out;

    // d_out is poisoned (0xAA) once and never re-poisoned between replays:
    // zero it every call (capture-safe async memset).
    hipMemsetAsync(out, 0, (size_t)out_size * sizeof(float), stream);

    const int groups  = N_TERMS / TERMS_PER_GROUP;        // 131072
    const int threads = groups * GROUP_LANES;             // 2,097,152
    const int block   = 256;
    const int grid    = (threads + block - 1) / block;    // 8192

    iafm_kernel<<<grid, block, 0, stream>>>(
        feat_idxs, intr_idxs, intr_divs, segment_ids,
        vecs, intr_W, intr_b, out);
}

// Round 2
// 139.973 us; speedup vs baseline: 1.0125x; 1.0125x over previous
//
#include <hip/hip_runtime.h>
#include <hip/hip_bf16.h>

// Problem constants (match reference)
#define N_TERMS 2097152
#define B_SEGS  8192
#define D_DIM   64
#define TPG     16   // terms per 16-lane group
#define GROUP_LANES 16

// Each 16-lane group handles 16 consecutive terms. Key restructure vs R0:
// out[s] = sum_d sum_t (w_t * v0[t][d] * v1[t][d]) + bias*count_s,
// so each lane accumulates its 4-float d-slice partial across the whole
// segment run; the 16-lane butterfly reduce happens only at segment
// boundaries (~0.4% of terms) instead of per term. Metadata is staged in
// LDS once and re-read per iteration as a uniform broadcast (1 ds_read_b128
// instead of 4 shuffles).
__global__ __launch_bounds__(256) void iafm_kernel(
    const int*   __restrict__ feat_idxs,   // [N,2]
    const int*   __restrict__ intr_idxs,   // [N]
    const float* __restrict__ intr_divs,   // [N]
    const int*   __restrict__ segment_ids, // [N] sorted
    const float* __restrict__ vecs,        // [N_FEATS, 64]
    const float* __restrict__ intr_W,      // [N_INTRS, 1]
    const float* __restrict__ intr_b,      // [1]
    float*       __restrict__ out)         // [B]
{
    __shared__ float4 meta[256];           // 16 groups/block x 16 terms

    const int lane  = threadIdx.x & 15;
    const int gbase = threadIdx.x & ~15;   // this group's LDS base
    const int gid   = (blockIdx.x * blockDim.x + threadIdx.x) >> 4;
    const int base  = gid * TPG;

    // Each lane loads metadata for term base+lane (coalesced), stages to LDS.
    const int   myterm = base + lane;
    const int2  fp = ((const int2*)feat_idxs)[myterm];
    const float w  = intr_W[intr_idxs[myterm]] / intr_divs[myterm];
    const int   sg = segment_ids[myterm];
    meta[threadIdx.x] = make_float4(__int_as_float(fp.x), __int_as_float(fp.y),
                                    w, __int_as_float(sg));
    __syncthreads();

    const float bias = intr_b[0];
    float acc = 0.0f;                      // per-lane partial: sum_t w_t * dot-slice
    int   cnt = 0;                         // terms in current run (uniform in group)
    int   cur = __shfl(sg, 0, GROUP_LANES);// segment of first term in group

    #pragma unroll
    for (int c = 0; c < TPG; ++c) {
        const float4 m  = meta[gbase + c]; // uniform within group -> LDS broadcast
        const int   f0  = __float_as_int(m.x);
        const int   f1  = __float_as_int(m.y);
        const int   seg = __float_as_int(m.w);

        // 16 lanes x float4 = one fully-coalesced 256B row per load.
        const float4 a = *(const float4*)(vecs + f0 * D_DIM + (lane << 2));
        const float4 v = *(const float4*)(vecs + f1 * D_DIM + (lane << 2));
        const float dl = a.x * v.x + a.y * v.y + a.z * v.z + a.w * v.w;

        if (seg != cur) {                  // rare (~0.4%/term): flush run
            float t = acc;
            t += __shfl_xor(t, 1, GROUP_LANES);
            t += __shfl_xor(t, 2, GROUP_LANES);
            t += __shfl_xor(t, 4, GROUP_LANES);
            t += __shfl_xor(t, 8, GROUP_LANES);
            if (lane == 0) atomicAdd(&out[cur], t + bias * (float)cnt);
            acc = 0.0f; cnt = 0; cur = seg;
        }
        acc = fmaf(m.z, dl, acc);
        ++cnt;
    }

    // final flush
    float t = acc;
    t += __shfl_xor(t, 1, GROUP_LANES);
    t += __shfl_xor(t, 2, GROUP_LANES);
    t += __shfl_xor(t, 4, GROUP_LANES);
    t += __shfl_xor(t, 8, GROUP_LANES);
    if (lane == 0) atomicAdd(&out[cur], t + bias * (float)cnt);
}

extern "C" void kernel_launch(void* const* d_in, const int* in_sizes, int n_in,
                              void* d_out, int out_size, void* d_ws, size_t ws_size,
                              hipStream_t stream) {
    const int*   feat_idxs   = (const int*)  d_in[0];
    const int*   intr_idxs   = (const int*)  d_in[1];
    const float* intr_divs   = (const float*)d_in[2];
    const int*   segment_ids = (const int*)  d_in[3];
    const float* vecs        = (const float*)d_in[4];
    const float* intr_W      = (const float*)d_in[5];
    const float* intr_b      = (const float*)d_in[6];
    float*       out         = (float*)d_out;

    // d_out is poisoned once and never re-poisoned between replays:
    // zero it every call (capture-safe async memset).
    hipMemsetAsync(out, 0, (size_t)out_size * sizeof(float), stream);

    const int groups  = N_TERMS / TPG;                    // 131072
    const int threads = groups * GROUP_LANES;             // 2,097,152
    const int block   = 256;
    const int grid    = (threads + block - 1) / block;    // 8192

    iafm_kernel<<<grid, block, 0, stream>>>(
        feat_idxs, intr_idxs, intr_divs, segment_ids,
        vecs, intr_W, intr_b, out);
}

// Round 3
// 104.108 us; speedup vs baseline: 1.3614x; 1.3445x over previous
//
#include <hip/hip_runtime.h>
#include <hip/hip_bf16.h>

// Problem constants (match reference)
#define N_TERMS 2097152
#define B_SEGS  8192
#define D_DIM   64
#define N_FEATS 100000

#define GL  8    // lanes per group (one bf16 row = 128B = 8 lanes x 16B)
#define TPG 8    // terms per group

// ---------- prep: vecs fp32 -> bf16 (RNE) into workspace ----------
__global__ __launch_bounds__(256) void cvt_bf16_kernel(
    const float* __restrict__ in, unsigned int* __restrict__ out, int n4)
{
    const int i = blockIdx.x * blockDim.x + threadIdx.x;
    if (i >= n4) return;
    const float4 f = ((const float4*)in)[i];
    __hip_bfloat162 p0 = __float22bfloat162_rn(make_float2(f.x, f.y));
    __hip_bfloat162 p1 = __float22bfloat162_rn(make_float2(f.z, f.w));
    uint2 o;
    o.x = *(const unsigned int*)&p0;
    o.y = *(const unsigned int*)&p1;
    ((uint2*)out)[i] = o;
}

__device__ __forceinline__ float bflo(unsigned int u) { return __uint_as_float(u << 16); }
__device__ __forceinline__ float bfhi(unsigned int u) { return __uint_as_float(u & 0xffff0000u); }

__device__ __forceinline__ float dot8(uint4 a, uint4 b) {
    float s;
    s  = bflo(a.x) * bflo(b.x) + bfhi(a.x) * bfhi(b.x);
    s += bflo(a.y) * bflo(b.y) + bfhi(a.y) * bfhi(b.y);
    s += bflo(a.z) * bflo(b.z) + bfhi(a.z) * bfhi(b.z);
    s += bflo(a.w) * bflo(b.w) + bfhi(a.w) * bfhi(b.w);
    return s;
}

// ---------- main: bf16 gathers, 8 lanes/term, load-all-then-compute ----------
__global__ __launch_bounds__(256, 4) void iafm_bf16_kernel(
    const int*   __restrict__ feat_idxs,   // [N,2]
    const int*   __restrict__ intr_idxs,   // [N]
    const float* __restrict__ intr_divs,   // [N]
    const int*   __restrict__ segment_ids, // [N] sorted
    const unsigned short* __restrict__ vb, // [N_FEATS*64] bf16
    const float* __restrict__ intr_W,      // [N_INTRS]
    const float* __restrict__ intr_b,      // [1]
    float*       __restrict__ out)         // [B]
{
    __shared__ float4 meta[256];           // 32 groups/block x 8 terms

    const int lane  = threadIdx.x & (GL - 1);
    const int gbase = threadIdx.x & ~(GL - 1);
    const int gid   = (blockIdx.x * blockDim.x + threadIdx.x) >> 3;
    const int base  = gid * TPG;

    // one term's metadata per lane (coalesced), staged to LDS
    const int   myterm = base + lane;
    const int2  fp = ((const int2*)feat_idxs)[myterm];
    const float w  = intr_W[intr_idxs[myterm]] / intr_divs[myterm];
    const int   sg = segment_ids[myterm];
    meta[threadIdx.x] = make_float4(__int_as_float(fp.x), __int_as_float(fp.y),
                                    w, __int_as_float(sg));
    __syncthreads();

    // phase 1: issue ALL 16 gathers (independent -> deep MLP)
    uint4 A[TPG], Bv[TPG];
    #pragma unroll
    for (int c = 0; c < TPG; ++c) {
        const float4 m = meta[gbase + c];
        const int f0 = __float_as_int(m.x);
        const int f1 = __float_as_int(m.y);
        A[c]  = *(const uint4*)(vb + f0 * D_DIM + lane * 8);
        Bv[c] = *(const uint4*)(vb + f1 * D_DIM + lane * 8);
    }

    // phase 2: compute; per-lane partial over this lane's 8-dim slice,
    // cross-lane reduce only at segment boundaries.
    const float bias = intr_b[0];
    float acc = 0.0f;
    int   cnt = 0;
    int   cur = __float_as_int(meta[gbase].w);

    #pragma unroll
    for (int c = 0; c < TPG; ++c) {
        const float4 m = meta[gbase + c];
        const int  seg = __float_as_int(m.w);
        const float dl = dot8(A[c], Bv[c]);
        if (seg != cur) {                  // rare: flush run
            float t = acc;
            t += __shfl_xor(t, 1, GL);
            t += __shfl_xor(t, 2, GL);
            t += __shfl_xor(t, 4, GL);
            if (lane == 0) atomicAdd(&out[cur], t + bias * (float)cnt);
            acc = 0.0f; cnt = 0; cur = seg;
        }
        acc = fmaf(m.z, dl, acc);
        ++cnt;
    }
    float t = acc;
    t += __shfl_xor(t, 1, GL);
    t += __shfl_xor(t, 2, GL);
    t += __shfl_xor(t, 4, GL);
    if (lane == 0) atomicAdd(&out[cur], t + bias * (float)cnt);
}

// ---------- fp32 fallback (R2 kernel) if workspace is too small ----------
__global__ __launch_bounds__(256) void iafm_f32_kernel(
    const int*   __restrict__ feat_idxs,
    const int*   __restrict__ intr_idxs,
    const float* __restrict__ intr_divs,
    const int*   __restrict__ segment_ids,
    const float* __restrict__ vecs,
    const float* __restrict__ intr_W,
    const float* __restrict__ intr_b,
    float*       __restrict__ out)
{
    __shared__ float4 meta[256];
    const int lane  = threadIdx.x & 15;
    const int gbase = threadIdx.x & ~15;
    const int gid   = (blockIdx.x * blockDim.x + threadIdx.x) >> 4;
    const int base  = gid * 16;
    const int myterm = base + lane;
    const int2  fp = ((const int2*)feat_idxs)[myterm];
    const float w  = intr_W[intr_idxs[myterm]] / intr_divs[myterm];
    const int   sg = segment_ids[myterm];
    meta[threadIdx.x] = make_float4(__int_as_float(fp.x), __int_as_float(fp.y),
                                    w, __int_as_float(sg));
    __syncthreads();
    const float bias = intr_b[0];
    float acc = 0.0f; int cnt = 0;
    int cur = __shfl(sg, 0, 16);
    #pragma unroll
    for (int c = 0; c < 16; ++c) {
        const float4 m = meta[gbase + c];
        const int f0 = __float_as_int(m.x), f1 = __float_as_int(m.y);
        const int seg = __float_as_int(m.w);
        const float4 a = *(const float4*)(vecs + f0 * D_DIM + (lane << 2));
        const float4 v = *(const float4*)(vecs + f1 * D_DIM + (lane << 2));
        const float dl = a.x * v.x + a.y * v.y + a.z * v.z + a.w * v.w;
        if (seg != cur) {
            float t = acc;
            t += __shfl_xor(t, 1, 16); t += __shfl_xor(t, 2, 16);
            t += __shfl_xor(t, 4, 16); t += __shfl_xor(t, 8, 16);
            if (lane == 0) atomicAdd(&out[cur], t + bias * (float)cnt);
            acc = 0.0f; cnt = 0; cur = seg;
        }
        acc = fmaf(m.z, dl, acc); ++cnt;
    }
    float t = acc;
    t += __shfl_xor(t, 1, 16); t += __shfl_xor(t, 2, 16);
    t += __shfl_xor(t, 4, 16); t += __shfl_xor(t, 8, 16);
    if (lane == 0) atomicAdd(&out[cur], t + bias * (float)cnt);
}

extern "C" void kernel_launch(void* const* d_in, const int* in_sizes, int n_in,
                              void* d_out, int out_size, void* d_ws, size_t ws_size,
                              hipStream_t stream) {
    const int*   feat_idxs   = (const int*)  d_in[0];
    const int*   intr_idxs   = (const int*)  d_in[1];
    const float* intr_divs   = (const float*)d_in[2];
    const int*   segment_ids = (const int*)  d_in[3];
    const float* vecs        = (const float*)d_in[4];
    const float* intr_W      = (const float*)d_in[5];
    const float* intr_b      = (const float*)d_in[6];
    float*       out         = (float*)d_out;

    hipMemsetAsync(out, 0, (size_t)out_size * sizeof(float), stream);

    const size_t need = (size_t)N_FEATS * D_DIM * sizeof(unsigned short); // 12.8 MB
    if (ws_size >= need) {
        // prep: vecs -> bf16 in workspace
        const int n4 = N_FEATS * D_DIM / 4;                  // 1.6M float4 groups
        cvt_bf16_kernel<<<(n4 + 255) / 256, 256, 0, stream>>>(
            vecs, (unsigned int*)d_ws, n4);

        const int groups  = N_TERMS / TPG;                   // 262144
        const int threads = groups * GL;                     // 2,097,152
        const int grid    = (threads + 255) / 256;           // 8192
        iafm_bf16_kernel<<<grid, 256, 0, stream>>>(
            feat_idxs, intr_idxs, intr_divs, segment_ids,
            (const unsigned short*)d_ws, intr_W, intr_b, out);
    } else {
        const int grid = (N_TERMS + 255) / 256;              // 8192 (16 lanes/term grp)
        iafm_f32_kernel<<<grid, 256, 0, stream>>>(
            feat_idxs, intr_idxs, intr_divs, segment_ids,
            vecs, intr_W, intr_b, out);
    }
}

// Round 4
// 78.932 us; speedup vs baseline: 1.7956x; 1.3190x over previous
//
#include <hip/hip_runtime.h>
#include <hip/hip_bf16.h>

// Problem constants (match reference)
#define N_TERMS 2097152
#define B_SEGS  8192
#define D_DIM   64
#define N_FEATS 100000

#define GL     8    // lanes per group (one bf16 row = 128B = 8 lanes x 16B)
#define BATCH  4    // terms per pipeline batch
#define NBATCH 8    // batches per group
#define TPGRP  (BATCH * NBATCH)   // 32 consecutive terms per group

// ---------- prep: vecs fp32 -> bf16 (RNE) into workspace ----------
__global__ __launch_bounds__(256) void cvt_bf16_kernel(
    const float* __restrict__ in, unsigned int* __restrict__ out, int n4)
{
    const int i = blockIdx.x * blockDim.x + threadIdx.x;
    if (i >= n4) return;
    const float4 f = ((const float4*)in)[i];
    __hip_bfloat162 p0 = __float22bfloat162_rn(make_float2(f.x, f.y));
    __hip_bfloat162 p1 = __float22bfloat162_rn(make_float2(f.z, f.w));
    uint2 o;
    o.x = *(const unsigned int*)&p0;
    o.y = *(const unsigned int*)&p1;
    ((uint2*)out)[i] = o;
}

__device__ __forceinline__ float bflo(unsigned int u) { return __uint_as_float(u << 16); }
__device__ __forceinline__ float bfhi(unsigned int u) { return __uint_as_float(u & 0xffff0000u); }

__device__ __forceinline__ float dot8(uint4 a, uint4 b) {
    float s;
    s  = bflo(a.x) * bflo(b.x) + bfhi(a.x) * bfhi(b.x);
    s += bflo(a.y) * bflo(b.y) + bfhi(a.y) * bfhi(b.y);
    s += bflo(a.z) * bflo(b.z) + bfhi(a.z) * bfhi(b.z);
    s += bflo(a.w) * bflo(b.w) + bfhi(a.w) * bfhi(b.w);
    return s;
}

// ---------- main: persistent pipelined bf16 gather kernel ----------
// Each 8-lane group owns 32 consecutive terms, processed as 8 batches of 4
// with a 3-buffer rotation: issue batch t+2 while computing batch t, so each
// wave keeps ~8 gather instructions in flight continuously (vs one burst in
// R3). No LDS/barriers -> waves pipeline independently.
__global__ __launch_bounds__(256, 3) void iafm_pipe_kernel(
    const int*   __restrict__ feat_idxs,   // [N,2]
    const int*   __restrict__ intr_idxs,   // [N]
    const float* __restrict__ intr_divs,   // [N]
    const int*   __restrict__ segment_ids, // [N] sorted
    const unsigned short* __restrict__ vb, // [N_FEATS*64] bf16
    const float* __restrict__ intr_W,      // [N_INTRS]
    const float* __restrict__ intr_b,      // [1]
    float*       __restrict__ out)         // [B]
{
    const int lane = threadIdx.x & (GL - 1);
    const int gid  = (blockIdx.x * blockDim.x + threadIdx.x) >> 3;
    const int base = gid * TPGRP;

    // prologue: per-lane metadata for terms base + lane + 8*i (coalesced)
    int2  fp[4];
    float w[4];
    int   sg[4];
    #pragma unroll
    for (int i = 0; i < 4; ++i) {
        const int t = base + lane + 8 * i;
        fp[i] = ((const int2*)feat_idxs)[t];
        sg[i] = segment_ids[t];
        w[i]  = intr_W[intr_idxs[t]] / intr_divs[t];
    }

    uint4 A[3][BATCH], Bv[3][BATCH];

    // batch t covers terms base+4t..base+4t+3; term j=4t+k lives in meta set
    // i=t>>1 at source lane (t&1)*4+k. All indices fold to constants on unroll.
    #define ISSUE(t) do { \
        const int i_ = (t) >> 1, s_ = ((t) & 1) * 4, b_ = (t) % 3; \
        _Pragma("unroll") \
        for (int k = 0; k < BATCH; ++k) { \
            const int f0 = __shfl(fp[i_].x, s_ + k, GL); \
            const int f1 = __shfl(fp[i_].y, s_ + k, GL); \
            A[b_][k]  = *(const uint4*)(vb + f0 * D_DIM + lane * 8); \
            Bv[b_][k] = *(const uint4*)(vb + f1 * D_DIM + lane * 8); \
        } \
    } while (0)

    const float bias = intr_b[0];
    float acc = 0.0f;
    int   cnt = 0;
    int   cur = __shfl(sg[0], 0, GL);

    ISSUE(0);
    ISSUE(1);

    #pragma unroll
    for (int t = 0; t < NBATCH; ++t) {
        const int i_ = t >> 1, s_ = (t & 1) * 4, b_ = t % 3;
        #pragma unroll
        for (int k = 0; k < BATCH; ++k) {
            const float dl = dot8(A[b_][k], Bv[b_][k]);
            const int   sj = __shfl(sg[i_], s_ + k, GL);
            const float wj = __shfl(w[i_],  s_ + k, GL);
            if (sj != cur) {               // uniform within the 8-lane group
                float r = acc;
                r += __shfl_xor(r, 1, GL);
                r += __shfl_xor(r, 2, GL);
                r += __shfl_xor(r, 4, GL);
                if (lane == 0) atomicAdd(&out[cur], r + bias * (float)cnt);
                acc = 0.0f; cnt = 0; cur = sj;
            }
            acc = fmaf(wj, dl, acc);
            ++cnt;
        }
        if (t + 2 < NBATCH) ISSUE(t + 2);  // buffer (t+2)%3 == (t-1)%3: free
    }

    float r = acc;
    r += __shfl_xor(r, 1, GL);
    r += __shfl_xor(r, 2, GL);
    r += __shfl_xor(r, 4, GL);
    if (lane == 0) atomicAdd(&out[cur], r + bias * (float)cnt);
    #undef ISSUE
}

// ---------- fp32 fallback if workspace is too small ----------
__global__ __launch_bounds__(256) void iafm_f32_kernel(
    const int*   __restrict__ feat_idxs,
    const int*   __restrict__ intr_idxs,
    const float* __restrict__ intr_divs,
    const int*   __restrict__ segment_ids,
    const float* __restrict__ vecs,
    const float* __restrict__ intr_W,
    const float* __restrict__ intr_b,
    float*       __restrict__ out)
{
    __shared__ float4 meta[256];
    const int lane  = threadIdx.x & 15;
    const int gbase = threadIdx.x & ~15;
    const int gid   = (blockIdx.x * blockDim.x + threadIdx.x) >> 4;
    const int base  = gid * 16;
    const int myterm = base + lane;
    const int2  fpx = ((const int2*)feat_idxs)[myterm];
    const float wx  = intr_W[intr_idxs[myterm]] / intr_divs[myterm];
    const int   sgx = segment_ids[myterm];
    meta[threadIdx.x] = make_float4(__int_as_float(fpx.x), __int_as_float(fpx.y),
                                    wx, __int_as_float(sgx));
    __syncthreads();
    const float bias = intr_b[0];
    float acc = 0.0f; int cnt = 0;
    int cur = __shfl(sgx, 0, 16);
    #pragma unroll
    for (int c = 0; c < 16; ++c) {
        const float4 m = meta[gbase + c];
        const int f0 = __float_as_int(m.x), f1 = __float_as_int(m.y);
        const int seg = __float_as_int(m.w);
        const float4 a = *(const float4*)(vecs + f0 * D_DIM + (lane << 2));
        const float4 v = *(const float4*)(vecs + f1 * D_DIM + (lane << 2));
        const float dl = a.x * v.x + a.y * v.y + a.z * v.z + a.w * v.w;
        if (seg != cur) {
            float t = acc;
            t += __shfl_xor(t, 1, 16); t += __shfl_xor(t, 2, 16);
            t += __shfl_xor(t, 4, 16); t += __shfl_xor(t, 8, 16);
            if (lane == 0) atomicAdd(&out[cur], t + bias * (float)cnt);
            acc = 0.0f; cnt = 0; cur = seg;
        }
        acc = fmaf(m.z, dl, acc); ++cnt;
    }
    float t = acc;
    t += __shfl_xor(t, 1, 16); t += __shfl_xor(t, 2, 16);
    t += __shfl_xor(t, 4, 16); t += __shfl_xor(t, 8, 16);
    if (lane == 0) atomicAdd(&out[cur], t + bias * (float)cnt);
}

extern "C" void kernel_launch(void* const* d_in, const int* in_sizes, int n_in,
                              void* d_out, int out_size, void* d_ws, size_t ws_size,
                              hipStream_t stream) {
    const int*   feat_idxs   = (const int*)  d_in[0];
    const int*   intr_idxs   = (const int*)  d_in[1];
    const float* intr_divs   = (const float*)d_in[2];
    const int*   segment_ids = (const int*)  d_in[3];
    const float* vecs        = (const float*)d_in[4];
    const float* intr_W      = (const float*)d_in[5];
    const float* intr_b      = (const float*)d_in[6];
    float*       out         = (float*)d_out;

    hipMemsetAsync(out, 0, (size_t)out_size * sizeof(float), stream);

    const size_t need = (size_t)N_FEATS * D_DIM * sizeof(unsigned short); // 12.8 MB
    if (ws_size >= need) {
        const int n4 = N_FEATS * D_DIM / 4;
        cvt_bf16_kernel<<<(n4 + 255) / 256, 256, 0, stream>>>(
            vecs, (unsigned int*)d_ws, n4);

        const int groups  = N_TERMS / TPGRP;                 // 65536
        const int threads = groups * GL;                     // 524288
        const int grid    = (threads + 255) / 256;           // 2048
        iafm_pipe_kernel<<<grid, 256, 0, stream>>>(
            feat_idxs, intr_idxs, intr_divs, segment_ids,
            (const unsigned short*)d_ws, intr_W, intr_b, out);
    } else {
        const int grid = (N_TERMS + 255) / 256;
        iafm_f32_kernel<<<grid, 256, 0, stream>>>(
            feat_idxs, intr_idxs, intr_divs, segment_ids,
            vecs, intr_W, intr_b, out);
    }
}

// Round 5
// 78.093 us; speedup vs baseline: 1.8149x; 1.0108x over previous
//
#include <hip/hip_runtime.h>
#include <hip/hip_bf16.h>

// Problem constants (match reference)
#define N_TERMS 2097152
#define B_SEGS  8192
#define D_DIM   64
#define N_FEATS 100000

#define GL     8    // lanes per group (one bf16 row = 128B = 8 lanes x 16B)
#define BATCH  4    // terms per pipeline batch
#define NBATCH 8    // batches per group
#define TPGRP  (BATCH * NBATCH)   // 32 consecutive terms per group

typedef unsigned int u32x4 __attribute__((ext_vector_type(4)));

// ---------- prep: vecs fp32 -> bf16 (RNE) into workspace ----------
__global__ __launch_bounds__(256) void cvt_bf16_kernel(
    const float* __restrict__ in, unsigned int* __restrict__ out, int n4)
{
    const int i = blockIdx.x * blockDim.x + threadIdx.x;
    if (i >= n4) return;
    const float4 f = ((const float4*)in)[i];
    __hip_bfloat162 p0 = __float22bfloat162_rn(make_float2(f.x, f.y));
    __hip_bfloat162 p1 = __float22bfloat162_rn(make_float2(f.z, f.w));
    uint2 o;
    o.x = *(const unsigned int*)&p0;
    o.y = *(const unsigned int*)&p1;
    ((uint2*)out)[i] = o;
}

__device__ __forceinline__ float bflo(unsigned int u) { return __uint_as_float(u << 16); }
__device__ __forceinline__ float bfhi(unsigned int u) { return __uint_as_float(u & 0xffff0000u); }

__device__ __forceinline__ float dot8(u32x4 a, u32x4 b) {
    float s;
    s  = bflo(a[0]) * bflo(b[0]) + bfhi(a[0]) * bfhi(b[0]);
    s += bflo(a[1]) * bflo(b[1]) + bfhi(a[1]) * bfhi(b[1]);
    s += bflo(a[2]) * bflo(b[2]) + bfhi(a[2]) * bfhi(b[2]);
    s += bflo(a[3]) * bflo(b[3]) + bfhi(a[3]) * bfhi(b[3]);
    return s;
}

// asm-pinned 16B gather: issue point fixed (asm volatile order), registers
// cannot be collapsed by the scheduler, completion handled by counted vmcnt.
__device__ __forceinline__ u32x4 gload16(const unsigned short* p) {
    u32x4 d;
    asm volatile("global_load_dwordx4 %0, %1, off" : "=v"(d) : "v"(p) : "memory");
    return d;
}

// counted waits (rule 18: sched_barrier after, so consumers can't hoist)
#define WAIT8() do { asm volatile("s_waitcnt vmcnt(8)" ::: "memory"); \
                     __builtin_amdgcn_sched_barrier(0); } while (0)
#define WAIT0() do { asm volatile("s_waitcnt vmcnt(0)" ::: "memory"); \
                     __builtin_amdgcn_sched_barrier(0); } while (0)

// ---------- main: asm-pinned double-buffered pipelined gather kernel ----------
// Each 8-lane group owns 32 consecutive terms: 8 batches of 4, double-buffered.
// Steady state per wave: 8-16 global_load_dwordx4 outstanding (8-16 KB), with
// batch t's compute gated by vmcnt(8) (batch t+1 stays in flight).
__global__ __launch_bounds__(256, 4) void iafm_pipe2_kernel(
    const int*   __restrict__ feat_idxs,   // [N,2]
    const int*   __restrict__ intr_idxs,   // [N]
    const float* __restrict__ intr_divs,   // [N]
    const int*   __restrict__ segment_ids, // [N] sorted
    const unsigned short* __restrict__ vb, // [N_FEATS*64] bf16
    const float* __restrict__ intr_W,      // [N_INTRS]
    const float* __restrict__ intr_b,      // [1]
    float*       __restrict__ out)         // [B]
{
    const int lane = threadIdx.x & (GL - 1);
    const int gid  = (blockIdx.x * blockDim.x + threadIdx.x) >> 3;
    const int base = gid * TPGRP;

    // prologue: per-lane metadata for terms base + lane + 8*i (coalesced)
    int2  fp[4];
    float w[4];
    int   sg[4];
    #pragma unroll
    for (int i = 0; i < 4; ++i) {
        const int t = base + lane + 8 * i;
        fp[i] = ((const int2*)feat_idxs)[t];
        sg[i] = segment_ids[t];
        w[i]  = intr_W[intr_idxs[t]] / intr_divs[t];
    }
    const float bias = intr_b[0];

    // Force ALL metadata values into registers (loads complete) before the
    // asm pipeline starts, so the compiler's waitcnt pass never needs to
    // inject a conservative vmcnt(0) inside the pinned loop.
    asm volatile("" :: "v"(fp[0].x), "v"(fp[0].y), "v"(fp[1].x), "v"(fp[1].y),
                       "v"(fp[2].x), "v"(fp[2].y), "v"(fp[3].x), "v"(fp[3].y),
                       "v"(sg[0]), "v"(sg[1]), "v"(sg[2]), "v"(sg[3]),
                       "v"(w[0]),  "v"(w[1]),  "v"(w[2]),  "v"(w[3]), "v"(bias));
    asm volatile("s_waitcnt vmcnt(0)" ::: "memory");

    u32x4 A[2][BATCH], Bv[2][BATCH];

    // batch t covers terms base+4t..base+4t+3; term j=4t+k lives in meta set
    // i=t>>1 at source lane (t&1)*4+k. Everything folds to constants on unroll.
    #define ISSUE(t_, sl_) do { \
        const int ii_ = (t_) >> 1, ss_ = ((t_) & 1) * 4; \
        _Pragma("unroll") \
        for (int k = 0; k < BATCH; ++k) { \
            const int f0_ = __shfl(fp[ii_].x, ss_ + k, GL); \
            const int f1_ = __shfl(fp[ii_].y, ss_ + k, GL); \
            A[sl_][k]  = gload16(vb + f0_ * D_DIM + lane * 8); \
            Bv[sl_][k] = gload16(vb + f1_ * D_DIM + lane * 8); \
        } \
    } while (0)

    float acc = 0.0f;
    int   cnt = 0;
    int   cur = __shfl(sg[0], 0, GL);

    ISSUE(0, 0);
    ISSUE(1, 1);

    #pragma unroll
    for (int t = 0; t < NBATCH; ++t) {
        if (t < NBATCH - 1) { WAIT8(); } else { WAIT0(); }
        const int slot = t & 1;            // literal after unroll (rule 20)
        const int i_   = t >> 1, s_ = (t & 1) * 4;
        #pragma unroll
        for (int k = 0; k < BATCH; ++k) {
            const float dl = dot8(A[slot][k], Bv[slot][k]);
            const int   sj = __shfl(sg[i_], s_ + k, GL);
            const float wj = __shfl(w[i_],  s_ + k, GL);
            if (sj != cur) {               // uniform within the 8-lane group
                float r = acc;
                r += __shfl_xor(r, 1, GL);
                r += __shfl_xor(r, 2, GL);
                r += __shfl_xor(r, 4, GL);
                if (lane == 0) atomicAdd(&out[cur], r + bias * (float)cnt);
                acc = 0.0f; cnt = 0; cur = sj;
            }
            acc = fmaf(wj, dl, acc);
            ++cnt;
        }
        if (t + 2 < NBATCH) ISSUE(t + 2, slot);  // refill the slot just consumed
    }
    #undef ISSUE

    float r = acc;
    r += __shfl_xor(r, 1, GL);
    r += __shfl_xor(r, 2, GL);
    r += __shfl_xor(r, 4, GL);
    if (lane == 0) atomicAdd(&out[cur], r + bias * (float)cnt);
}

// ---------- fp32 fallback if workspace is too small ----------
__global__ __launch_bounds__(256) void iafm_f32_kernel(
    const int*   __restrict__ feat_idxs,
    const int*   __restrict__ intr_idxs,
    const float* __restrict__ intr_divs,
    const int*   __restrict__ segment_ids,
    const float* __restrict__ vecs,
    const float* __restrict__ intr_W,
    const float* __restrict__ intr_b,
    float*       __restrict__ out)
{
    __shared__ float4 meta[256];
    const int lane  = threadIdx.x & 15;
    const int gbase = threadIdx.x & ~15;
    const int gid   = (blockIdx.x * blockDim.x + threadIdx.x) >> 4;
    const int base  = gid * 16;
    const int myterm = base + lane;
    const int2  fpx = ((const int2*)feat_idxs)[myterm];
    const float wx  = intr_W[intr_idxs[myterm]] / intr_divs[myterm];
    const int   sgx = segment_ids[myterm];
    meta[threadIdx.x] = make_float4(__int_as_float(fpx.x), __int_as_float(fpx.y),
                                    wx, __int_as_float(sgx));
    __syncthreads();
    const float bias = intr_b[0];
    float acc = 0.0f; int cnt = 0;
    int cur = __shfl(sgx, 0, 16);
    #pragma unroll
    for (int c = 0; c < 16; ++c) {
        const float4 m = meta[gbase + c];
        const int f0 = __float_as_int(m.x), f1 = __float_as_int(m.y);
        const int seg = __float_as_int(m.w);
        const float4 a = *(const float4*)(vecs + f0 * D_DIM + (lane << 2));
        const float4 v = *(const float4*)(vecs + f1 * D_DIM + (lane << 2));
        const float dl = a.x * v.x + a.y * v.y + a.z * v.z + a.w * v.w;
        if (seg != cur) {
            float t = acc;
            t += __shfl_xor(t, 1, 16); t += __shfl_xor(t, 2, 16);
            t += __shfl_xor(t, 4, 16); t += __shfl_xor(t, 8, 16);
            if (lane == 0) atomicAdd(&out[cur], t + bias * (float)cnt);
            acc = 0.0f; cnt = 0; cur = seg;
        }
        acc = fmaf(m.z, dl, acc); ++cnt;
    }
    float t = acc;
    t += __shfl_xor(t, 1, 16); t += __shfl_xor(t, 2, 16);
    t += __shfl_xor(t, 4, 16); t += __shfl_xor(t, 8, 16);
    if (lane == 0) atomicAdd(&out[cur], t + bias * (float)cnt);
}

extern "C" void kernel_launch(void* const* d_in, const int* in_sizes, int n_in,
                              void* d_out, int out_size, void* d_ws, size_t ws_size,
                              hipStream_t stream) {
    const int*   feat_idxs   = (const int*)  d_in[0];
    const int*   intr_idxs   = (const int*)  d_in[1];
    const float* intr_divs   = (const float*)d_in[2];
    const int*   segment_ids = (const int*)  d_in[3];
    const float* vecs        = (const float*)d_in[4];
    const float* intr_W      = (const float*)d_in[5];
    const float* intr_b      = (const float*)d_in[6];
    float*       out         = (float*)d_out;

    hipMemsetAsync(out, 0, (size_t)out_size * sizeof(float), stream);

    const size_t need = (size_t)N_FEATS * D_DIM * sizeof(unsigned short); // 12.8 MB
    if (ws_size >= need) {
        const int n4 = N_FEATS * D_DIM / 4;
        cvt_bf16_kernel<<<(n4 + 255) / 256, 256, 0, stream>>>(
            vecs, (unsigned int*)d_ws, n4);

        const int groups  = N_TERMS / TPGRP;                 // 65536
        const int threads = groups * GL;                     // 524288
        const int grid    = (threads + 255) / 256;           // 2048
        iafm_pipe2_kernel<<<grid, 256, 0, stream>>>(
            feat_idxs, intr_idxs, intr_divs, segment_ids,
            (const unsigned short*)d_ws, intr_W, intr_b, out);
    } else {
        const int grid = (N_TERMS + 255) / 256;
        iafm_f32_kernel<<<grid, 256, 0, stream>>>(
            feat_idxs, intr_idxs, intr_divs, segment_ids,
            vecs, intr_W, intr_b, out);
    }
}